// Round 5
// baseline (137.652 us; speedup 1.0000x reference)
//
#include <hip/hip_runtime.h>
#include <stdint.h>

// Problem constants (reference: B,N,D,OUT = 4,512,128,128)
#define B_ 4
#define N_ 512
#define D_ 128
#define O_ 128
#define OS 16     // o-slice width per block
#define IT 64     // i-rows per block

typedef __attribute__((address_space(3))) uint32_t* lds_ptr_t;
typedef const __attribute__((address_space(1))) uint32_t* gbl_ptr_t;

// ---------------------------------------------------------------------------
// Stage one 64-row x 128-float adj chunk (32 KB) into LDS via
// global_load_lds_dwordx4. Dest is LINEAR (wave-uniform base + lane*16 --
// hardware requirement); bank-conflict fix is done by swizzling the GLOBAL
// source chunk index instead (rule: swizzle both-sides-or-neither, and the
// dest side can't be swizzled). Involution: slot s holds logical chunk
// s ^ ((row&3)<<2); reader XORs the same.
// Per wave: 2 issues x 64 lanes x 16B = 2 KB -> rows {2w, 2w+1} + 32i.
// ---------------------------------------------------------------------------
__device__ __forceinline__ void stage_adj_chunk(const float* __restrict__ adj_tile,
                                                float* dst, int jc, int tid) {
    const int w = tid >> 6;
    const int l = tid & 63;
#pragma unroll
    for (int i = 0; i < 2; ++i) {
        const int row = i * 32 + 2 * w + (l >> 5);
        const int g   = (l & 31) ^ ((row & 3) << 2);     // source-side swizzle
        const float* src = adj_tile + (size_t)row * N_ + jc * 128 + g * 4;
        float* d = dst + i * 4096 + w * 256;             // wave-uniform base
        __builtin_amdgcn_global_load_lds((gbl_ptr_t)(const void*)src,
                                         (lds_ptr_t)(void*)d, 16, 0, 0);
    }
}

// ---------------------------------------------------------------------------
// Single fused kernel. Block = (b, i-tile 64, o-slice 16); grid 256.
// Phase A: q-slice = x[b] @ W2[:,os] for ALL 512 rows -> qsT LDS (transposed);
//          waves whose rows fall in the i-tile also keep phat.
// Phase C: maskmax against LDS-staged adj chunks (double-buffered async
//          staging; R4 post-mortem: vector broadcast loads of adj from L2/L3
//          were the 30 us stall -- LDS broadcast is free).
// Mask trick unchanged: adj in {0,1}; cand = fma(adj,1024,q); |q|,|phat|<<1024;
// empty rows -> negative -> relu -> 0 == reference.
// ---------------------------------------------------------------------------
__global__ __launch_bounds__(1024)
void edgeconv_fused(const float* __restrict__ x, const float* __restrict__ adj,
                    const float* __restrict__ W, const float* __restrict__ bias,
                    float* __restrict__ out) {
    __shared__ float W2s[D_][OS];          // 8 KB
    __shared__ float Wds[D_][OS];          // 8 KB
    __shared__ float qsT[OS][N_ + 4];      // 33 KB  (stride 516: even 8-per-bank spread)
    __shared__ float phs[IT][OS];          // 4 KB
    __shared__ float part[IT][OS][5];      // 20 KB
    __shared__ float adjs[2][IT][128];     // 64 KB  (row stride 512B EXACT: linear dest)

    const int tid   = threadIdx.x;
    const int bid   = blockIdx.x;
    const int os    = bid & 7;
    const int it    = (bid >> 3) & 7;
    const int b     = bid >> 6;
    const int obase = os * OS;
    const int i0    = it * IT;

    const float* __restrict__ adj_tile = adj + ((size_t)b * N_ + i0) * N_;

    // ---- prologue: async-stage adj chunks 0,1 (land during phase A) ----
    stage_adj_chunk(adj_tile, &adjs[0][0][0], 0, tid);
    stage_adj_chunk(adj_tile, &adjs[1][0][0], 1, tid);

    // ---- stage W slices: thread -> (k, o-pair) ----
    {
        const int k  = tid >> 3;                         // 0..127
        const int oc = (tid & 7) * 2;                    // 0..14
        const float2 w1 = *(const float2*)&W[(size_t)k * O_ + obase + oc];
        const float2 w2 = *(const float2*)&W[(size_t)(k + D_) * O_ + obase + oc];
        *(float2*)&W2s[k][oc] = w2;
        *(float2*)&Wds[k][oc] = make_float2(w1.x - w2.x, w1.y - w2.y);
    }
    __syncthreads();

    // ---- Phase A: thread = (j-pair, o-quad) ----
    const int jb  = (tid >> 2) * 2;                      // 0..510
    const int oq4 = (tid & 3) * 4;                       // 0,4,8,12
    const float* __restrict__ X0 = x + ((size_t)b * N_ + jb) * D_;
    const float* __restrict__ X1 = X0 + D_;

    float aq[2][4] = {{0,0,0,0},{0,0,0,0}};
    float ap[2][4] = {{0,0,0,0},{0,0,0,0}};
    const bool in_tile = (jb >= i0) && (jb < i0 + IT);   // wave-uniform

    if (in_tile) {
#pragma unroll 4
        for (int kc = 0; kc < 16; ++kc) {                // 8 k's per chunk
            float xr0[8], xr1[8];
            *(float4*)&xr0[0] = *(const float4*)&X0[kc * 8];
            *(float4*)&xr0[4] = *(const float4*)&X0[kc * 8 + 4];
            *(float4*)&xr1[0] = *(const float4*)&X1[kc * 8];
            *(float4*)&xr1[4] = *(const float4*)&X1[kc * 8 + 4];
#pragma unroll
            for (int kk = 0; kk < 8; ++kk) {
                const float4 wq = *(const float4*)&W2s[kc * 8 + kk][oq4];
                const float4 wd = *(const float4*)&Wds[kc * 8 + kk][oq4];
                const float x0 = xr0[kk], x1 = xr1[kk];
                aq[0][0] = fmaf(x0, wq.x, aq[0][0]);
                aq[0][1] = fmaf(x0, wq.y, aq[0][1]);
                aq[0][2] = fmaf(x0, wq.z, aq[0][2]);
                aq[0][3] = fmaf(x0, wq.w, aq[0][3]);
                aq[1][0] = fmaf(x1, wq.x, aq[1][0]);
                aq[1][1] = fmaf(x1, wq.y, aq[1][1]);
                aq[1][2] = fmaf(x1, wq.z, aq[1][2]);
                aq[1][3] = fmaf(x1, wq.w, aq[1][3]);
                ap[0][0] = fmaf(x0, wd.x, ap[0][0]);
                ap[0][1] = fmaf(x0, wd.y, ap[0][1]);
                ap[0][2] = fmaf(x0, wd.z, ap[0][2]);
                ap[0][3] = fmaf(x0, wd.w, ap[0][3]);
                ap[1][0] = fmaf(x1, wd.x, ap[1][0]);
                ap[1][1] = fmaf(x1, wd.y, ap[1][1]);
                ap[1][2] = fmaf(x1, wd.z, ap[1][2]);
                ap[1][3] = fmaf(x1, wd.w, ap[1][3]);
            }
        }
    } else {
#pragma unroll 4
        for (int kc = 0; kc < 16; ++kc) {
            float xr0[8], xr1[8];
            *(float4*)&xr0[0] = *(const float4*)&X0[kc * 8];
            *(float4*)&xr0[4] = *(const float4*)&X0[kc * 8 + 4];
            *(float4*)&xr1[0] = *(const float4*)&X1[kc * 8];
            *(float4*)&xr1[4] = *(const float4*)&X1[kc * 8 + 4];
#pragma unroll
            for (int kk = 0; kk < 8; ++kk) {
                const float4 wq = *(const float4*)&W2s[kc * 8 + kk][oq4];
                const float x0 = xr0[kk], x1 = xr1[kk];
                aq[0][0] = fmaf(x0, wq.x, aq[0][0]);
                aq[0][1] = fmaf(x0, wq.y, aq[0][1]);
                aq[0][2] = fmaf(x0, wq.z, aq[0][2]);
                aq[0][3] = fmaf(x0, wq.w, aq[0][3]);
                aq[1][0] = fmaf(x1, wq.x, aq[1][0]);
                aq[1][1] = fmaf(x1, wq.y, aq[1][1]);
                aq[1][2] = fmaf(x1, wq.z, aq[1][2]);
                aq[1][3] = fmaf(x1, wq.w, aq[1][3]);
            }
        }
    }

    // q-slice -> LDS transposed
#pragma unroll
    for (int c = 0; c < 4; ++c)
        *(float2*)&qsT[oq4 + c][jb] = make_float2(aq[0][c], aq[1][c]);

    if (in_tile) {
        const int il = jb - i0;
#pragma unroll
        for (int c = 0; c < 4; ++c) {
            phs[il][oq4 + c]     = ap[0][c];
            phs[il + 1][oq4 + c] = ap[1][c];
        }
    }
    __syncthreads();   // qsT ready; adj chunks 0,1 drained (vmcnt(0) at barrier)

    // ---- Phase C: thread = (wave i-quad, oo, js); adj from LDS ----
    {
        const int oo = tid & 15;
        const int js = (tid >> 4) & 3;
        const int ib = (tid >> 6) * 4;                   // wave-uniform i-quad

        // per-row bases; swizzled read index = js*4 + 16*(tl ^ rr): all
        // offsets compile-time immediates off these bases.
        const float* bq = &qsT[oo][js * 4];

        float m0 = -1e30f, m1 = -1e30f, m2 = -1e30f, m3 = -1e30f;

        for (int jc = 0; jc < 4; ++jc) {
            const float* ab = &adjs[jc & 1][0][0];
            const float* b0 = ab + (size_t)(ib + 0) * 128 + js * 4;
            const float* b1 = ab + (size_t)(ib + 1) * 128 + js * 4;
            const float* b2 = ab + (size_t)(ib + 2) * 128 + js * 4;
            const float* b3 = ab + (size_t)(ib + 3) * 128 + js * 4;
            const float* q0 = bq + jc * 128;
#pragma unroll
            for (int tl = 0; tl < 8; ++tl) {
                const float4 qv = *(const float4*)&q0[tl * 16];
                const float4 a0 = *(const float4*)&b0[16 * (tl ^ 0)];
                const float4 a1 = *(const float4*)&b1[16 * (tl ^ 1)];
                const float4 a2 = *(const float4*)&b2[16 * (tl ^ 2)];
                const float4 a3 = *(const float4*)&b3[16 * (tl ^ 3)];
                m0 = fmaxf(m0, fmaxf(fmaxf(fmaf(a0.x, 1024.0f, qv.x), fmaf(a0.y, 1024.0f, qv.y)),
                                     fmaxf(fmaf(a0.z, 1024.0f, qv.z), fmaf(a0.w, 1024.0f, qv.w))));
                m1 = fmaxf(m1, fmaxf(fmaxf(fmaf(a1.x, 1024.0f, qv.x), fmaf(a1.y, 1024.0f, qv.y)),
                                     fmaxf(fmaf(a1.z, 1024.0f, qv.z), fmaf(a1.w, 1024.0f, qv.w))));
                m2 = fmaxf(m2, fmaxf(fmaxf(fmaf(a2.x, 1024.0f, qv.x), fmaf(a2.y, 1024.0f, qv.y)),
                                     fmaxf(fmaf(a2.z, 1024.0f, qv.z), fmaf(a2.w, 1024.0f, qv.w))));
                m3 = fmaxf(m3, fmaxf(fmaxf(fmaf(a3.x, 1024.0f, qv.x), fmaf(a3.y, 1024.0f, qv.y)),
                                     fmaxf(fmaf(a3.z, 1024.0f, qv.z), fmaf(a3.w, 1024.0f, qv.w))));
            }
            // all waves done with chunk jc -> safe to overwrite its buffer.
            // chunk jc+1's staging (issued >=1 chunk-compute ago) is drained
            // by this barrier's vmcnt(0) -> ready for next iteration.
            __syncthreads();
            if (jc < 2)
                stage_adj_chunk(adj_tile, &adjs[jc & 1][0][0], jc + 2, tid);
        }

        part[ib + 0][oo][js] = m0;
        part[ib + 1][oo][js] = m1;
        part[ib + 2][oo][js] = m2;
        part[ib + 3][oo][js] = m3;
    }
    __syncthreads();

    // ---- epilogue: 1 output per thread ----
    {
        const int il = tid >> 4;                         // 0..63
        const int oo = tid & 15;
        const float mm = fmaxf(fmaxf(part[il][oo][0], part[il][oo][1]),
                               fmaxf(part[il][oo][2], part[il][oo][3]));
        const float v = phs[il][oo] + bias[obase + oo] + mm - 1024.0f;
        out[((size_t)b * N_ + i0 + il) * O_ + obase + oo] = fmaxf(v, 0.0f);
    }
}

// ---------------------------------------------------------------------------
extern "C" void kernel_launch(void* const* d_in, const int* in_sizes, int n_in,
                              void* d_out, int out_size, void* d_ws, size_t ws_size,
                              hipStream_t stream) {
    const float* x    = (const float*)d_in[0];   // (B,N,D)
    const float* adj  = (const float*)d_in[1];   // (B,N,N)
    const float* W    = (const float*)d_in[2];   // (2D, OUT)
    const float* bias = (const float*)d_in[3];   // (OUT,)
    float* out = (float*)d_out;                  // (B,N,OUT)

    (void)d_ws; (void)ws_size;                   // no workspace: everything in LDS

    edgeconv_fused<<<B_ * 8 * 8, 1024, 0, stream>>>(x, adj, W, bias, out);
}

// Round 6
// 73.839 us; speedup vs baseline: 1.8642x; 1.8642x over previous
//
#include <hip/hip_runtime.h>

// Problem constants (reference: B,N,D,OUT = 4,512,128,128)
#define B_ 4
#define N_ 512
#define D_ 128
#define O_ 128

// ---------------------------------------------------------------------------
// K1: q = x @ W2 ; phat = x @ (W1 - W2) + bias
// 256 blocks x 1024 threads: o = tid&127 (coalesced W loads), kq = tid>>7
// splits K=128 8 ways (16 k's each) -> 16 waves/CU. x values are wave-uniform
// -> scalar loads. Dual LDS buffers (72 KB) -> ONE barrier for both reduces.
// q/phat are stored NONTEMPORAL: consumers (K2) are on other XCDs; nt pushes
// the lines toward L3 at write time so K2's first touch is an L3 hit instead
// of a cross-XCD dirty-L2 snoop (~900 cyc).
// ---------------------------------------------------------------------------
#define R1 8

__global__ __launch_bounds__(1024)
void gemm_pq_kernel(const float* __restrict__ x, const float* __restrict__ W,
                    const float* __restrict__ bias, float* __restrict__ q,
                    float* __restrict__ phat) {
    const int tid = threadIdx.x;
    const int o   = tid & (O_ - 1);
    const int kq  = __builtin_amdgcn_readfirstlane(tid >> 7);  // 0..7, uniform
    const int row0 = blockIdx.x * R1;

    const float* __restrict__ xb = x + (size_t)row0 * D_;

    float accp[R1], accq[R1];
#pragma unroll
    for (int r = 0; r < R1; ++r) { accp[r] = 0.0f; accq[r] = 0.0f; }

    const int k0 = kq * (D_ / 8);               // 16 k's per group
#pragma unroll 4
    for (int k = k0; k < k0 + D_ / 8; ++k) {
        const float w1 = W[(size_t)k * O_ + o];          // coalesced, L2-hot
        const float w2 = W[(size_t)(k + D_) * O_ + o];
        const float wd = w1 - w2;
#pragma unroll
        for (int r = 0; r < R1; ++r) {
            const float xv = xb[(size_t)r * D_ + k];     // uniform -> s_load
            accp[r] = fmaf(xv, wd, accp[r]);
            accq[r] = fmaf(xv, w2, accq[r]);
        }
    }

    // pad inner dim to 9: lane stride 9 floats -> only the free 2-way alias
    __shared__ float redq[R1][O_][9];                    // 36 KB
    __shared__ float redp[R1][O_][9];                    // 36 KB

#pragma unroll
    for (int r = 0; r < R1; ++r) {
        redq[r][o][kq] = accq[r];
        redp[r][o][kq] = accp[r];
    }
    __syncthreads();                            // the ONLY barrier

    {   // exactly R1*O_ = 1024 (r,o) pairs for 1024 threads
        const int rr = tid >> 7;
        const int oo = tid & (O_ - 1);
        const float sq = ((redq[rr][oo][0] + redq[rr][oo][1]) +
                          (redq[rr][oo][2] + redq[rr][oo][3])) +
                         ((redq[rr][oo][4] + redq[rr][oo][5]) +
                          (redq[rr][oo][6] + redq[rr][oo][7]));
        const float sp = ((redp[rr][oo][0] + redp[rr][oo][1]) +
                          (redp[rr][oo][2] + redp[rr][oo][3])) +
                         ((redp[rr][oo][4] + redp[rr][oo][5]) +
                          (redp[rr][oo][6] + redp[rr][oo][7]));
        const size_t idx = (size_t)(row0 + rr) * O_ + oo;
        __builtin_nontemporal_store(sq, &q[idx]);
        __builtin_nontemporal_store(sp + bias[oo], &phat[idx]);
    }
}

// ---------------------------------------------------------------------------
// K2: out[b,i,o] = relu(phat[b,i,o] + max_{j:adj[b,i,j]!=0} q[b,j,o])
// Mask trick: adj in {0,1}; cand = fma(adj, 1024, qv); masked-in candidates
// dominate by >1000 (|q| <= ~5). Epilogue subtracts 1024. Empty neighbor
// row -> phat + maxq - 1024 < 0 -> relu -> 0, matching the reference.
//
// 256 blocks x 1024 threads: o = tid&127, jq = tid>>7 (wave-uniform -> adj
// loads ride the scalar pipe as s_load_dwordx8). TI=8 i-rows/block; j split
// 8 ways (64 each), processed in batches of 16 with prefetch-next-16:
// 16-32 q-loads in flight covers the cold L3 latency (~400 cyc)
// that an 8-deep pipeline couldn't (compute per 8-batch is only ~200 cyc).
// ---------------------------------------------------------------------------
#define TI 8
#define JS 8
#define JB 16     // j-batch width

__global__ __launch_bounds__(1024)
void maskmax_kernel(const float* __restrict__ q, const float* __restrict__ phat,
                    const float* __restrict__ adj, float* __restrict__ out) {
    const int tid = threadIdx.x;
    const int o   = tid & (O_ - 1);
    const int jq  = __builtin_amdgcn_readfirstlane(tid >> 7);   // 0..7
    const int b   = blockIdx.x >> 6;            // N/TI = 64 tiles per batch
    const int i0  = (blockIdx.x & 63) * TI;

    const float* __restrict__ qb   = q + (size_t)b * N_ * O_ + o;
    const float* __restrict__ arow = adj + ((size_t)b * N_ + i0) * N_;

    float m[TI];
#pragma unroll
    for (int i = 0; i < TI; ++i) m[i] = -1e30f;

    const int j0   = jq * (N_ / JS);            // 64 j's per group
    const int jend = j0 + (N_ / JS);

    float qv[JB], qn[JB];
#pragma unroll
    for (int u = 0; u < JB; ++u)
        qv[u] = qb[(size_t)(j0 + u) * O_];      // prologue: 16 in flight

    for (int j = j0; j < jend; j += JB) {       // 4 iterations
        // prefetch next batch (uniform select, no branch; wraps harmlessly)
        const int jn = (j + JB < jend) ? (j + JB) : j0;
#pragma unroll
        for (int u = 0; u < JB; ++u)
            qn[u] = qb[(size_t)(jn + u) * O_];

#pragma unroll
        for (int i = 0; i < TI; ++i) {
            const float* __restrict__ ar = arow + (size_t)i * N_ + j; // uniform -> s_load
            float c[JB];
#pragma unroll
            for (int u = 0; u < JB; ++u)
                c[u] = fmaf(ar[u], 1024.0f, qv[u]);
            float mi = m[i];
#pragma unroll
            for (int u = 0; u < JB; u += 4) {   // pairs -> v_max3 folding
                mi = fmaxf(mi, fmaxf(c[u],     c[u + 1]));
                mi = fmaxf(mi, fmaxf(c[u + 2], c[u + 3]));
            }
            m[i] = mi;
        }

#pragma unroll
        for (int u = 0; u < JB; ++u) qv[u] = qn[u];  // rotate
    }

    // combine the 8 j-groups; pad inner dim to 9 -> only the free 2-way alias
    __shared__ float part[TI][O_][JS + 1];      // 36 KB
#pragma unroll
    for (int i = 0; i < TI; ++i) part[i][o][jq] = m[i];
    __syncthreads();

    {   // exactly TI*O_ = 1024 (i,o) pairs for 1024 threads
        const int i  = tid >> 7;
        const int oo = tid & (O_ - 1);
        float mm = -1e30f;
#pragma unroll
        for (int p = 0; p < JS; ++p) mm = fmaxf(mm, part[i][oo][p]);
        const size_t idx = ((size_t)b * N_ + i0 + i) * O_ + oo;
        const float v = phat[idx] + mm - 1024.0f;
        out[idx] = v > 0.0f ? v : 0.0f;
    }
}

// ---------------------------------------------------------------------------
extern "C" void kernel_launch(void* const* d_in, const int* in_sizes, int n_in,
                              void* d_out, int out_size, void* d_ws, size_t ws_size,
                              hipStream_t stream) {
    const float* x    = (const float*)d_in[0];   // (B,N,D)
    const float* adj  = (const float*)d_in[1];   // (B,N,N)
    const float* W    = (const float*)d_in[2];   // (2D, OUT)
    const float* bias = (const float*)d_in[3];   // (OUT,)
    float* out = (float*)d_out;                  // (B,N,OUT)

    float* q    = (float*)d_ws;                        // B*N*O_ floats = 1 MB
    float* phat = q + (size_t)B_ * N_ * O_;            // 1 MB

    gemm_pq_kernel<<<(B_ * N_) / R1, 1024, 0, stream>>>(x, W, bias, q, phat);
    maskmax_kernel<<<B_ * (N_ / TI), 1024, 0, stream>>>(q, phat, adj, out);
}